// Round 1
// baseline (403.040 us; speedup 1.0000x reference)
//
#include <hip/hip_runtime.h>
#include <hip/hip_bf16.h>
#include <cmath>

#define N_NODES 8192
#define NFEAT 512
#define NHID 512
#define NCLASS 64
#define NLAYERS 8
#define CAP 96

typedef __attribute__((ext_vector_type(8))) short bf16x8;
typedef __attribute__((ext_vector_type(4))) float f32x4;
typedef unsigned short u16;

__device__ inline float bf2f(short u) {
  union { unsigned int i; float f; } x;
  x.i = ((unsigned int)(u16)u) << 16;
  return x.f;
}
__device__ inline short f2bf(float f) {
  union { float f; unsigned int i; } x;
  x.f = f;
  unsigned int r = x.i + 0x7FFFu + ((x.i >> 16) & 1u);
  return (short)(r >> 16);
}

// ---------------- adjacency extraction: one streaming pass over adj ----------
__global__ __launch_bounds__(256)
void extract_kernel(const float* __restrict__ adj, int* __restrict__ idx,
                    int* __restrict__ cnt, int* __restrict__ colcnt)
{
  __shared__ int s_cnt;
  const int i = blockIdx.x;
  if (threadIdx.x == 0) s_cnt = 0;
  __syncthreads();
  const float4* row = (const float4*)(adj + (size_t)i * N_NODES);
  for (int c = threadIdx.x; c < N_NODES / 4; c += 256) {
    float4 v = row[c];
    float vals[4] = {v.x, v.y, v.z, v.w};
    #pragma unroll
    for (int e = 0; e < 4; ++e) {
      if (vals[e] != 0.0f) {
        int p = atomicAdd(&s_cnt, 1);
        if (p < CAP) idx[(size_t)i * CAP + p] = c * 4 + e;
        atomicAdd(&colcnt[c * 4 + e], 1);
      }
    }
  }
  __syncthreads();
  if (threadIdx.x == 0) cnt[i] = min(s_cnt, CAP);
}

__global__ __launch_bounds__(256)
void dinv_kernel(const int* __restrict__ colcnt, float* __restrict__ dinv)
{
  int j = blockIdx.x * 256 + threadIdx.x;
  if (j < N_NODES) dinv[j] = 1.0f / sqrtf((float)colcnt[j] + 1.0f); // +1 for identity
}

// ---------------- f32 -> bf16 cast (x) ---------------------------------------
__global__ __launch_bounds__(256)
void cvt_bf16_kernel(const float* __restrict__ src, u16* __restrict__ dst, int n4)
{
  int i = blockIdx.x * 256 + threadIdx.x;
  if (i >= n4) return;
  float4 v = ((const float4*)src)[i];
  ushort4 o;
  o.x = (u16)f2bf(v.x); o.y = (u16)f2bf(v.y);
  o.z = (u16)f2bf(v.z); o.w = (u16)f2bf(v.w);
  ((ushort4*)dst)[i] = o;
}

// ---------------- weight transpose + cast: Wt[n][k] = W[k][n] ---------------
__global__ __launch_bounds__(256)
void transpose_cast_kernel(const float* __restrict__ fc1W, const float* __restrict__ convW,
                           u16* __restrict__ Wt)
{
  __shared__ float tile[32][33];
  const int m = blockIdx.z;
  const float* src = (m == 0) ? fc1W : convW + (size_t)(m - 1) * NHID * NHID;
  u16* dst = Wt + (size_t)m * NHID * NHID;
  const int k0 = blockIdx.x * 32, n0 = blockIdx.y * 32;
  const int tx = threadIdx.x & 31, ty = threadIdx.x >> 5; // 32 x 8
  #pragma unroll
  for (int r = 0; r < 32; r += 8)
    tile[ty + r][tx] = src[(size_t)(k0 + ty + r) * NHID + n0 + tx];
  __syncthreads();
  #pragma unroll
  for (int r = 0; r < 32; r += 8)
    dst[(size_t)(n0 + ty + r) * NHID + k0 + tx] = (u16)f2bf(tile[tx][ty + r]);
}

// ---------------- MFMA GEMM: C = A[8192x512] @ Wt^T, fused epilogues --------
#define AS1 __attribute__((address_space(1)))
#define AS3 __attribute__((address_space(3)))

__device__ inline void load16(const void* g, void* l) {
  __builtin_amdgcn_global_load_lds((const AS1 void*)g, (AS3 void*)l, 16, 0, 0);
}

// MODE 0: out = relu(A@W + bias)        -> outF (f32) and outB (bf16)
// MODE 1: out = relu(cA*skip + cB*A@W)  -> outB (bf16)
template<int MODE>
__global__ __launch_bounds__(256, 2)
void gemm_kernel(const u16* __restrict__ A, const u16* __restrict__ Bt,
                 const float* __restrict__ bias,
                 const u16* __restrict__ skip,
                 float cA, float cB,
                 float* __restrict__ outF, u16* __restrict__ outB)
{
  constexpr int K = 512, N = 512;
  __shared__ u16 ldsA[128 * 32];
  __shared__ u16 ldsB[128 * 32];
  const int tid = threadIdx.x;
  const int wave = tid >> 6, lane = tid & 63;
  const int m0 = blockIdx.x * 128, n0 = blockIdx.y * 128;
  const int wr = wave >> 1, wc = wave & 1;
  const int lrow = lane & 15, lk = lane >> 4;

  f32x4 acc[4][4];
  #pragma unroll
  for (int a = 0; a < 4; ++a)
    #pragma unroll
    for (int b = 0; b < 4; ++b)
      acc[a][b] = (f32x4){0.f, 0.f, 0.f, 0.f};

  for (int ks = 0; ks < K; ks += 32) {
    #pragma unroll
    for (int r = 0; r < 2; ++r) {
      const int g = r * 256 + wave * 64 + lane;     // chunk id (16B chunks)
      const int row = g >> 2, cc = g & 3;
      load16(A  + (size_t)(m0 + row) * K + ks + cc * 8, &ldsA[(size_t)(r * 256 + wave * 64) * 8]);
      load16(Bt + (size_t)(n0 + row) * K + ks + cc * 8, &ldsB[(size_t)(r * 256 + wave * 64) * 8]);
    }
    __syncthreads();
    bf16x8 af[4], bfr[4];
    #pragma unroll
    for (int mi = 0; mi < 4; ++mi)
      af[mi] = *(const bf16x8*)&ldsA[(wr * 64 + mi * 16 + lrow) * 32 + lk * 8];
    #pragma unroll
    for (int ni = 0; ni < 4; ++ni)
      bfr[ni] = *(const bf16x8*)&ldsB[(wc * 64 + ni * 16 + lrow) * 32 + lk * 8];
    #pragma unroll
    for (int mi = 0; mi < 4; ++mi)
      #pragma unroll
      for (int ni = 0; ni < 4; ++ni)
        acc[mi][ni] = __builtin_amdgcn_mfma_f32_16x16x32_bf16(af[mi], bfr[ni], acc[mi][ni], 0, 0, 0);
    __syncthreads();
  }

  #pragma unroll
  for (int mi = 0; mi < 4; ++mi) {
    #pragma unroll
    for (int ni = 0; ni < 4; ++ni) {
      #pragma unroll
      for (int r = 0; r < 4; ++r) {
        const int row = m0 + wr * 64 + mi * 16 + lk * 4 + r;  // C/D: row=(lane>>4)*4+reg
        const int col = n0 + wc * 64 + ni * 16 + lrow;        //      col=lane&15
        const size_t o = (size_t)row * N + col;
        float v = acc[mi][ni][r];
        if (MODE == 0) {
          v += bias[col];
          v = fmaxf(v, 0.f);
          outF[o] = v;
          outB[o] = (u16)f2bf(v);
        } else {
          float s = bf2f((short)skip[o]);
          v = cA * s + cB * v;
          v = fmaxf(v, 0.f);
          outB[o] = (u16)f2bf(v);
        }
      }
    }
  }
}

// ---------------- SpMM: init_res = 0.9 * (P @ H) + 0.1 * H0 -----------------
__global__ __launch_bounds__(256)
void spmm_kernel(const u16* __restrict__ H, const float* __restrict__ H0,
                 const float* __restrict__ dinv, const int* __restrict__ idx,
                 const int* __restrict__ cnt, u16* __restrict__ outB)
{
  const int wave = threadIdx.x >> 6, lane = threadIdx.x & 63;
  const int i = blockIdx.x * 4 + wave;
  const int c0 = lane * 8;
  float acc[8];
  #pragma unroll
  for (int e = 0; e < 8; ++e) acc[e] = 0.f;
  const int n = cnt[i];
  const int* nb = idx + (size_t)i * CAP;
  for (int t = 0; t < n; ++t) {
    const int j = nb[t];
    const float w = dinv[j];
    bf16x8 hv = *(const bf16x8*)&H[(size_t)j * NHID + c0];
    #pragma unroll
    for (int e = 0; e < 8; ++e) acc[e] += w * bf2f(hv[e]);
  }
  const float di = dinv[i];
  bf16x8 hr = *(const bf16x8*)&H[(size_t)i * NHID + c0];
  const float4 h0a = *(const float4*)&H0[(size_t)i * NHID + c0];
  const float4 h0b = *(const float4*)&H0[(size_t)i * NHID + c0 + 4];
  float h0[8] = {h0a.x, h0a.y, h0a.z, h0a.w, h0b.x, h0b.y, h0b.z, h0b.w};
  bf16x8 ov;
  #pragma unroll
  for (int e = 0; e < 8; ++e) {
    float v = di * (acc[e] + di * bf2f(hr[e]));   // P@H row (incl. identity term)
    v = 0.9f * v + 0.1f * h0[e];                  // (1-alpha), alpha
    ov[e] = f2bf(v);
  }
  *(bf16x8*)&outB[(size_t)i * NHID + c0] = ov;
}

// ---------------- fc2 + -log_softmax fused ----------------------------------
__global__ __launch_bounds__(256)
void fc2_softmax_kernel(const u16* __restrict__ H, const float* __restrict__ W,
                        const float* __restrict__ b, float* __restrict__ out)
{
  __shared__ float sh[4][4][512];
  const int wave = threadIdx.x >> 6, lane = threadIdx.x & 63;
  const int rowBase = blockIdx.x * 16 + wave * 4;
  #pragma unroll
  for (int rr = 0; rr < 4; ++rr) {
    bf16x8 hv = *(const bf16x8*)&H[(size_t)(rowBase + rr) * NHID + lane * 8];
    #pragma unroll
    for (int e = 0; e < 8; ++e) sh[wave][rr][lane * 8 + e] = bf2f(hv[e]);
  }
  __syncthreads();
  const float bb = b[lane];
  float a0 = bb, a1 = bb, a2 = bb, a3 = bb;
  #pragma unroll 8
  for (int k = 0; k < 512; ++k) {
    const float w = W[k * 64 + lane];
    a0 += sh[wave][0][k] * w;
    a1 += sh[wave][1][k] * w;
    a2 += sh[wave][2][k] * w;
    a3 += sh[wave][3][k] * w;
  }
  float accs[4] = {a0, a1, a2, a3};
  #pragma unroll
  for (int rr = 0; rr < 4; ++rr) {
    const float v = accs[rr];
    float mx = v;
    for (int off = 32; off > 0; off >>= 1) mx = fmaxf(mx, __shfl_xor(mx, off));
    float s = __expf(v - mx);
    for (int off = 32; off > 0; off >>= 1) s += __shfl_xor(s, off);
    out[(size_t)(rowBase + rr) * NCLASS + lane] = -(v - mx - logf(s));
  }
}

// ---------------- launch -----------------------------------------------------
extern "C" void kernel_launch(void* const* d_in, const int* in_sizes, int n_in,
                              void* d_out, int out_size, void* d_ws, size_t ws_size,
                              hipStream_t stream)
{
  const float* x     = (const float*)d_in[0];
  const float* adj   = (const float*)d_in[1];
  const float* fc1W  = (const float*)d_in[2];
  const float* fc1b  = (const float*)d_in[3];
  const float* convW = (const float*)d_in[4];
  const float* fc2W  = (const float*)d_in[5];
  const float* fc2b  = (const float*)d_in[6];
  float* out = (float*)d_out;

  char* ws = (char*)d_ws;
  size_t off = 0;
  auto alloc = [&](size_t bytes) -> void* {
    void* p = ws + off;
    off = (off + bytes + 255) & ~(size_t)255;
    return p;
  };
  u16*   xb   = (u16*)alloc((size_t)N_NODES * NFEAT * 2);
  u16*   Wt   = (u16*)alloc((size_t)9 * NHID * NHID * 2);
  float* H0   = (float*)alloc((size_t)N_NODES * NHID * 4);
  u16*   H    = (u16*)alloc((size_t)N_NODES * NHID * 2);
  u16*   IR   = (u16*)alloc((size_t)N_NODES * NHID * 2);
  int*   idx  = (int*)alloc((size_t)N_NODES * CAP * 4);
  int*   cnt  = (int*)alloc((size_t)N_NODES * 4);
  int*   colc = (int*)alloc((size_t)N_NODES * 4);
  float* dinv = (float*)alloc((size_t)N_NODES * 4);

  hipMemsetAsync(colc, 0, N_NODES * 4, stream);
  extract_kernel<<<N_NODES, 256, 0, stream>>>(adj, idx, cnt, colc);
  dinv_kernel<<<N_NODES / 256, 256, 0, stream>>>(colc, dinv);
  cvt_bf16_kernel<<<(N_NODES * NFEAT / 4) / 256, 256, 0, stream>>>(x, xb, N_NODES * NFEAT / 4);
  transpose_cast_kernel<<<dim3(16, 16, 9), 256, 0, stream>>>(fc1W, convW, Wt);

  // fc1: H0 = relu(x @ fc1_W + b), H = bf16(H0)
  gemm_kernel<0><<<dim3(64, 4), 256, 0, stream>>>(xb, Wt, fc1b, nullptr, 0.f, 0.f, H0, H);

  for (int i = 0; i < NLAYERS; ++i) {
    spmm_kernel<<<N_NODES / 4, 256, 0, stream>>>(H, H0, dinv, idx, cnt, IR);
    const double beta = log(0.5 / (double)(i + 1) + 1.0);
    gemm_kernel<1><<<dim3(64, 4), 256, 0, stream>>>(
        IR, Wt + (size_t)(i + 1) * NHID * NHID, nullptr, IR,
        (float)(1.0 - beta), (float)beta, nullptr, H);
  }

  fc2_softmax_kernel<<<N_NODES / 16, 256, 0, stream>>>(H, fc2W, fc2b, out);
}